// Round 4
// baseline (435.188 us; speedup 1.0000x reference)
//
#include <hip/hip_runtime.h>

// Problem constants (from reference)
#define HH 256
#define WW 336
#define HWPIX (HH * WW)          // 86016
#define BATCH 8
#define NEV 262144               // 2^18
#define NEV_SHIFT 18
#define FLOW_SCALING 336.0f
#define REG_WEIGHT 0.001f

#define BANDS 32
#define BANDSHIFT 3
#define BANDROWS 8
#define TILEPIX (BANDROWS * WW)    // 2688
#define NBINS (2 * BATCH * BANDS)  // 512 bins: (tr*8+b)*32+band
#define CAP 10240                  // slots/bin; mean ~9.0K, sigma ~96 -> ~12 sigma

// Workspace layout:
//   [0]      uint  gcount[NBINS]          (2 KB)
//   [4096]   uint2 items[NBINS * CAP]     (42 MB)  (wy_f32, qx<<12|qt<<1|p)

__device__ __forceinline__ float wave_reduce_sum(float v) {
    #pragma unroll
    for (int o = 32; o > 0; o >>= 1) v += __shfl_down(v, o, 64);
    return v;
}

// Pass 1: warp events, bin by (tr, b, 8-row band). Items straddling a band
// boundary are duplicated into both bands.
__global__ __launch_bounds__(256)
void bin_events(const float* __restrict__ flow,
                const float4* __restrict__ ev,
                const float2* __restrict__ pmask,
                unsigned int* __restrict__ gcount,
                uint2* __restrict__ items) {
    __shared__ int lcnt[64];    // local bins: tr*32 + band (b fixed per block)
    __shared__ int lbase[64];
    int tid = threadIdx.x;
    if (tid < 64) lcnt[tid] = 0;
    __syncthreads();

    int bn = blockIdx.x * 256 + tid;
    int b = bn >> NEV_SHIFT;     // uniform across block

    float4 e = ev[bn];           // t, y, x, pol
    float t = e.x, y = e.y, x = e.z;
    float2 m = pmask[bn];
    unsigned int p = (m.x > 0.5f) ? 0u : 1u;

    int iy = (int)y, ix = (int)x;   // exact integers in range
    const float* fb = flow + b * 2 * HWPIX + iy * WW + ix;
    float fx = fb[0];               // channel 0: x-flow
    float fy = fb[HWPIX];           // channel 1: y-flow

    int lbA[2] = {-1, -1}, lbB[2] = {-1, -1};
    int slA[2], slB[2];
    uint2 val[2];

    #pragma unroll
    for (int tr = 0; tr < 2; ++tr) {
        float tref  = tr ? 0.0f : 1.0f;
        float tg    = tr ? (1.0f - t) : t;
        float dtS = (tref - t) * FLOW_SCALING;
        float wy = fmaf(dtS, fy, y);
        float wx = fmaf(dtS, fx, x);
        if (!(wx > -1.0f && wx < (float)WW)) continue;
        if (!(wy > -1.0f && wy < (float)HH)) continue;

        int ty = (int)floorf(wy);
        int band0 = -1, band1 = -1;
        if (ty >= 0 && ty < HH) band0 = ty >> BANDSHIFT;
        int r1 = ty + 1;
        if (r1 >= 0 && r1 < HH) {
            int bb = r1 >> BANDSHIFT;
            if (bb != band0) band1 = bb;
        }

        unsigned int qx = (unsigned int)(fmaf(wx, 2048.0f, 2048.5f)); // round((wx+1)*2048)
        unsigned int qt = (unsigned int)(tg * 2047.0f + 0.5f);
        val[tr] = make_uint2(__float_as_uint(wy), (qx << 12) | (qt << 1) | p);

        if (band0 >= 0) {
            lbA[tr] = tr * BANDS + band0;
            slA[tr] = atomicAdd(&lcnt[lbA[tr]], 1);
        }
        if (band1 >= 0) {
            lbB[tr] = tr * BANDS + band1;
            slB[tr] = atomicAdd(&lcnt[lbB[tr]], 1);
        }
    }
    __syncthreads();

    if (tid < 64) {
        int c = lcnt[tid];
        // gbin = tr*256 + b*32 + band ; tid = tr*32 + band
        int gbin = (tid >> 5) * (BATCH * BANDS) + b * BANDS + (tid & 31);
        lbase[tid] = c > 0 ? (int)atomicAdd(&gcount[gbin], (unsigned int)c) : 0;
    }
    __syncthreads();

    #pragma unroll
    for (int tr = 0; tr < 2; ++tr) {
        if (lbA[tr] >= 0) {
            int lb = lbA[tr];
            int slot = lbase[lb] + slA[tr];
            if (slot < CAP) {
                int gbin = (lb >> 5) * (BATCH * BANDS) + b * BANDS + (lb & 31);
                items[(size_t)gbin * CAP + slot] = val[tr];
            }
        }
        if (lbB[tr] >= 0) {
            int lb = lbB[tr];
            int slot = lbase[lb] + slB[tr];
            if (slot < CAP) {
                int gbin = (lb >> 5) * (BATCH * BANDS) + b * BANDS + (lb & 31);
                items[(size_t)gbin * CAP + slot] = val[tr];
            }
        }
    }
}

__device__ __forceinline__ void accum_item(float* __restrict__ s, int lo,
                                           unsigned int wyu, unsigned int pk) {
    float wy = __uint_as_float(wyu);
    float wx = (float)(pk >> 12) * (1.0f / 2048.0f) - 1.0f;
    float tg = (float)((pk >> 1) & 2047u) * (1.0f / 2047.0f);
    int p = pk & 1u;

    float tyf = floorf(wy);
    float fy = wy - tyf;
    int ty = (int)tyf;
    float lxf = floorf(wx);
    float fxx = wx - lxf;
    int lx = (int)lxf;

    float* L = s + p * (2 * TILEPIX);

    #pragma unroll
    for (int a = 0; a < 2; ++a) {
        int ry = ty + a;
        if ((unsigned)(ry - lo) >= (unsigned)BANDROWS) continue;
        float wrow = a ? fy : (1.0f - fy);
        int rb = (ry - lo) * WW;
        #pragma unroll
        for (int c = 0; c < 2; ++c) {
            int cx = lx + c;
            if ((unsigned)cx >= (unsigned)WW) continue;
            float w = wrow * (c ? fxx : (1.0f - fxx));
            int pix = rb + cx;
            atomicAdd(&L[pix], w);
            atomicAdd(&L[TILEPIX + pix], w * tg);
        }
    }
}

// Pass 2: one block per bin, 1024 threads, 43 KB LDS -> 2 blocks/CU, 32 waves.
// uint4 loads (2 items) + software prefetch. Fused ratio^2 loss.
__global__ __launch_bounds__(1024)
void bin_accum(const unsigned int* __restrict__ gcount,
               const uint2* __restrict__ items,
               float* __restrict__ out) {
    __shared__ float s[2 * 2 * TILEPIX];   // [p][iwe|its][pix] : 43 KB

    int band = blockIdx.x;
    int tr   = blockIdx.y;
    int b    = blockIdx.z;
    int tid  = threadIdx.x;

    for (int i = tid; i < 2 * 2 * TILEPIX; i += 1024) s[i] = 0.0f;
    __syncthreads();

    int gbin = (tr * BATCH + b) * BANDS + band;
    int cnt = min((int)gcount[gbin], CAP);
    const uint2* bp = items + (size_t)gbin * CAP;
    const uint4* bp4 = (const uint4*)bp;
    const int lo = band * BANDROWS;

    int npair = cnt >> 1;
    int n = tid;
    uint4 cur = make_uint4(0u, 0u, 0u, 0u);
    if (n < npair) cur = bp4[n];
    while (n < npair) {
        int nn = n + 1024;
        uint4 nxt = make_uint4(0u, 0u, 0u, 0u);
        if (nn < npair) nxt = bp4[nn];
        accum_item(s, lo, cur.x, cur.y);
        accum_item(s, lo, cur.z, cur.w);
        n = nn;
        cur = nxt;
    }
    if ((cnt & 1) && tid == 0) {
        uint2 u = bp[cnt - 1];
        accum_item(s, lo, u.x, u.y);
    }
    __syncthreads();

    float v = 0.0f;
    for (int i = tid; i < 2 * TILEPIX; i += 1024) {
        int p = i / TILEPIX, pix = i - (i >= TILEPIX ? TILEPIX : 0);
        const float* L = s + p * (2 * TILEPIX);
        float iwe = L[pix];
        float its = L[TILEPIX + pix];
        float r = its / (iwe + 1e-9f);
        v += r * r;
    }
    v = wave_reduce_sum(v);
    if ((tid & 63) == 0) atomicAdd(out, v);
}

__global__ void smooth_loss(const float* __restrict__ flow, float* __restrict__ out) {
    const int TOT = BATCH * 2 * HWPIX;
    float v = 0.0f;
    for (int i = blockIdx.x * blockDim.x + threadIdx.x; i < TOT;
         i += gridDim.x * blockDim.x) {
        int pix = i % HWPIX;
        int col = pix % WW;
        int row = pix / WW;
        float f = flow[i];
        if (row < HH - 1) {
            float d = f - flow[i + WW];
            v += sqrtf(d * d + 1e-6f);
        }
        if (col < WW - 1) {
            float d = f - flow[i + 1];
            v += sqrtf(d * d + 1e-6f);
        }
    }
    v = wave_reduce_sum(v);
    if ((threadIdx.x & 63) == 0) atomicAdd(out, REG_WEIGHT * v);
}

extern "C" void kernel_launch(void* const* d_in, const int* in_sizes, int n_in,
                              void* d_out, int out_size, void* d_ws, size_t ws_size,
                              hipStream_t stream) {
    const float*  flow  = (const float*)d_in[0];
    const float4* ev    = (const float4*)d_in[1];
    const float2* pmask = (const float2*)d_in[2];
    float* out = (float*)d_out;

    unsigned int* gcount = (unsigned int*)d_ws;
    uint2* items = (uint2*)((char*)d_ws + 4096);

    hipMemsetAsync(gcount, 0, NBINS * sizeof(unsigned int), stream);
    hipMemsetAsync(d_out, 0, sizeof(float), stream);

    int total_ev = BATCH * NEV;
    bin_events<<<total_ev / 256, 256, 0, stream>>>(flow, ev, pmask, gcount, items);

    dim3 g2(BANDS, 2, BATCH);
    bin_accum<<<g2, 1024, 0, stream>>>(gcount, items, out);

    smooth_loss<<<1024, 256, 0, stream>>>(flow, out);
}

// Round 5
// 354.931 us; speedup vs baseline: 1.2261x; 1.2261x over previous
//
#include <hip/hip_runtime.h>

// Problem constants (from reference)
#define HH 256
#define WW 336
#define HWPIX (HH * WW)          // 86016
#define BATCH 8
#define NEV 262144               // 2^18
#define NEV_SHIFT 18
#define FLOW_SCALING 336.0f
#define REG_WEIGHT 0.001f

#define BANDS 32
#define BANDSHIFT 3
#define BANDROWS 8
#define TILEPIX (BANDROWS * WW)    // 2688
#define NBINS (2 * BATCH * BANDS)  // 512 bins: (tr*8+b)*32+band
#define CAP 10240                  // slots/bin; mean ~9.0K

// Workspace layout:
//   [0]      uint  gcount[NBINS]          (2 KB)
//   [4096]   uint2 items[NBINS * CAP]     (42 MB)  (wy_f32, qx<<12|qt<<1|p)

__device__ __forceinline__ float wave_reduce_sum(float v) {
    #pragma unroll
    for (int o = 32; o > 0; o >>= 1) v += __shfl_down(v, o, 64);
    return v;
}

// Pass 1: warp events, bin by (tr, b, 8-row band). Items straddling a band
// boundary are duplicated into both bands.
__global__ __launch_bounds__(256)
void bin_events(const float* __restrict__ flow,
                const float4* __restrict__ ev,
                const float2* __restrict__ pmask,
                unsigned int* __restrict__ gcount,
                uint2* __restrict__ items) {
    __shared__ int lcnt[64];    // local bins: tr*32 + band (b fixed per block)
    __shared__ int lbase[64];
    int tid = threadIdx.x;
    if (tid < 64) lcnt[tid] = 0;
    __syncthreads();

    int bn = blockIdx.x * 256 + tid;
    int b = bn >> NEV_SHIFT;     // uniform across block

    float4 e = ev[bn];           // t, y, x, pol
    float t = e.x, y = e.y, x = e.z;
    float2 m = pmask[bn];
    unsigned int p = (m.x > 0.5f) ? 0u : 1u;

    int iy = (int)y, ix = (int)x;   // exact integers in range
    const float* fb = flow + b * 2 * HWPIX + iy * WW + ix;
    float fx = fb[0];               // channel 0: x-flow
    float fy = fb[HWPIX];           // channel 1: y-flow

    int lbA[2] = {-1, -1}, lbB[2] = {-1, -1};
    int slA[2], slB[2];
    uint2 val[2];

    #pragma unroll
    for (int tr = 0; tr < 2; ++tr) {
        float tref  = tr ? 0.0f : 1.0f;
        float tg    = tr ? (1.0f - t) : t;
        float dtS = (tref - t) * FLOW_SCALING;
        float wy = fmaf(dtS, fy, y);
        float wx = fmaf(dtS, fx, x);
        if (!(wx > -1.0f && wx < (float)WW)) continue;
        if (!(wy > -1.0f && wy < (float)HH)) continue;

        int ty = (int)floorf(wy);
        int band0 = -1, band1 = -1;
        if (ty >= 0 && ty < HH) band0 = ty >> BANDSHIFT;
        int r1 = ty + 1;
        if (r1 >= 0 && r1 < HH) {
            int bb = r1 >> BANDSHIFT;
            if (bb != band0) band1 = bb;
        }

        unsigned int qx = (unsigned int)(fmaf(wx, 2048.0f, 2048.5f)); // round((wx+1)*2048)
        unsigned int qt = (unsigned int)(tg * 2047.0f + 0.5f);
        val[tr] = make_uint2(__float_as_uint(wy), (qx << 12) | (qt << 1) | p);

        if (band0 >= 0) {
            lbA[tr] = tr * BANDS + band0;
            slA[tr] = atomicAdd(&lcnt[lbA[tr]], 1);
        }
        if (band1 >= 0) {
            lbB[tr] = tr * BANDS + band1;
            slB[tr] = atomicAdd(&lcnt[lbB[tr]], 1);
        }
    }
    __syncthreads();

    if (tid < 64) {
        int c = lcnt[tid];
        // gbin = tr*256 + b*32 + band ; tid = tr*32 + band
        int gbin = (tid >> 5) * (BATCH * BANDS) + b * BANDS + (tid & 31);
        lbase[tid] = c > 0 ? (int)atomicAdd(&gcount[gbin], (unsigned int)c) : 0;
    }
    __syncthreads();

    #pragma unroll
    for (int tr = 0; tr < 2; ++tr) {
        if (lbA[tr] >= 0) {
            int lb = lbA[tr];
            int slot = lbase[lb] + slA[tr];
            if (slot < CAP) {
                int gbin = (lb >> 5) * (BATCH * BANDS) + b * BANDS + (lb & 31);
                items[(size_t)gbin * CAP + slot] = val[tr];
            }
        }
        if (lbB[tr] >= 0) {
            int lb = lbB[tr];
            int slot = lbase[lb] + slB[tr];
            if (slot < CAP) {
                int gbin = (lb >> 5) * (BATCH * BANDS) + b * BANDS + (lb & 31);
                items[(size_t)gbin * CAP + slot] = val[tr];
            }
        }
    }
}

__device__ __forceinline__ void accum_item(float* __restrict__ s, int lo,
                                           unsigned int wyu, unsigned int pk) {
    float wy = __uint_as_float(wyu);
    float wx = (float)(pk >> 12) * (1.0f / 2048.0f) - 1.0f;
    float tg = (float)((pk >> 1) & 2047u) * (1.0f / 2047.0f);
    int p = pk & 1u;

    float tyf = floorf(wy);
    float fy = wy - tyf;
    int ty = (int)tyf;
    float lxf = floorf(wx);
    float fxx = wx - lxf;
    int lx = (int)lxf;

    float* L = s + p * (2 * TILEPIX);

    #pragma unroll
    for (int a = 0; a < 2; ++a) {
        int ry = ty + a;
        if ((unsigned)(ry - lo) >= (unsigned)BANDROWS) continue;
        float wrow = a ? fy : (1.0f - fy);
        int rb = (ry - lo) * WW;
        #pragma unroll
        for (int c = 0; c < 2; ++c) {
            int cx = lx + c;
            if ((unsigned)cx >= (unsigned)WW) continue;
            float w = wrow * (c ? fxx : (1.0f - fxx));
            int pix = rb + cx;
            atomicAdd(&L[pix], w);
            atomicAdd(&L[TILEPIX + pix], w * tg);
        }
    }
}

// Pass 2: one block per bin, 1024 threads, 43 KB LDS -> 2 blocks/CU.
// uint4 loads (2 items) + software prefetch. Fused ratio^2 loss.
// ONE global atomic per block (LDS tree for the 16 wave sums).
__global__ __launch_bounds__(1024)
void bin_accum(const unsigned int* __restrict__ gcount,
               const uint2* __restrict__ items,
               float* __restrict__ out) {
    __shared__ float s[2 * 2 * TILEPIX];   // [p][iwe|its][pix] : 43 KB
    __shared__ float red[16];

    int band = blockIdx.x;
    int tr   = blockIdx.y;
    int b    = blockIdx.z;
    int tid  = threadIdx.x;

    for (int i = tid; i < 2 * 2 * TILEPIX; i += 1024) s[i] = 0.0f;
    __syncthreads();

    int gbin = (tr * BATCH + b) * BANDS + band;
    int cnt = min((int)gcount[gbin], CAP);
    const uint2* bp = items + (size_t)gbin * CAP;
    const uint4* bp4 = (const uint4*)bp;
    const int lo = band * BANDROWS;

    int npair = cnt >> 1;
    int n = tid;
    uint4 cur = make_uint4(0u, 0u, 0u, 0u);
    if (n < npair) cur = bp4[n];
    while (n < npair) {
        int nn = n + 1024;
        uint4 nxt = make_uint4(0u, 0u, 0u, 0u);
        if (nn < npair) nxt = bp4[nn];
        accum_item(s, lo, cur.x, cur.y);
        accum_item(s, lo, cur.z, cur.w);
        n = nn;
        cur = nxt;
    }
    if ((cnt & 1) && tid == 0) {
        uint2 u = bp[cnt - 1];
        accum_item(s, lo, u.x, u.y);
    }
    __syncthreads();

    float v = 0.0f;
    for (int i = tid; i < 2 * TILEPIX; i += 1024) {
        int p = i / TILEPIX, pix = i - (i >= TILEPIX ? TILEPIX : 0);
        const float* L = s + p * (2 * TILEPIX);
        float iwe = L[pix];
        float its = L[TILEPIX + pix];
        float r = its / (iwe + 1e-9f);
        v += r * r;
    }
    v = wave_reduce_sum(v);
    if ((tid & 63) == 0) red[tid >> 6] = v;
    __syncthreads();
    if (tid < 16) {
        float r = red[tid];
        r += __shfl_down(r, 8, 64);
        r += __shfl_down(r, 4, 64);
        r += __shfl_down(r, 2, 64);
        r += __shfl_down(r, 1, 64);
        if (tid == 0) atomicAdd(out, r);
    }
}

__global__ __launch_bounds__(256)
void smooth_loss(const float* __restrict__ flow, float* __restrict__ out) {
    __shared__ float red[4];
    const int TOT = BATCH * 2 * HWPIX;
    float v = 0.0f;
    for (int i = blockIdx.x * blockDim.x + threadIdx.x; i < TOT;
         i += gridDim.x * blockDim.x) {
        int pix = i % HWPIX;
        int col = pix % WW;
        int row = pix / WW;
        float f = flow[i];
        if (row < HH - 1) {
            float d = f - flow[i + WW];
            v += sqrtf(d * d + 1e-6f);
        }
        if (col < WW - 1) {
            float d = f - flow[i + 1];
            v += sqrtf(d * d + 1e-6f);
        }
    }
    int tid = threadIdx.x;
    v = wave_reduce_sum(v);
    if ((tid & 63) == 0) red[tid >> 6] = v;
    __syncthreads();
    if (tid < 4) {
        float r = red[tid];
        r += __shfl_down(r, 2, 64);
        r += __shfl_down(r, 1, 64);
        if (tid == 0) atomicAdd(out, REG_WEIGHT * r);
    }
}

extern "C" void kernel_launch(void* const* d_in, const int* in_sizes, int n_in,
                              void* d_out, int out_size, void* d_ws, size_t ws_size,
                              hipStream_t stream) {
    const float*  flow  = (const float*)d_in[0];
    const float4* ev    = (const float4*)d_in[1];
    const float2* pmask = (const float2*)d_in[2];
    float* out = (float*)d_out;

    unsigned int* gcount = (unsigned int*)d_ws;
    uint2* items = (uint2*)((char*)d_ws + 4096);

    hipMemsetAsync(gcount, 0, NBINS * sizeof(unsigned int), stream);
    hipMemsetAsync(d_out, 0, sizeof(float), stream);

    int total_ev = BATCH * NEV;
    bin_events<<<total_ev / 256, 256, 0, stream>>>(flow, ev, pmask, gcount, items);

    dim3 g2(BANDS, 2, BATCH);
    bin_accum<<<g2, 1024, 0, stream>>>(gcount, items, out);

    smooth_loss<<<256, 256, 0, stream>>>(flow, out);
}

// Round 6
// 197.846 us; speedup vs baseline: 2.1996x; 1.7940x over previous
//
#include <hip/hip_runtime.h>

// Problem constants (from reference)
#define HH 256
#define WW 336
#define HWPIX (HH * WW)          // 86016
#define BATCH 8
#define NEV 262144               // 2^18
#define NEV_SHIFT 18
#define FLOW_SCALING 336.0f
#define REG_WEIGHT 0.001f

#define BANDS 32
#define BANDSHIFT 3
#define BANDROWS 8
#define TILEPIX (BANDROWS * WW)    // 2688
#define NBINS (2 * BATCH * BANDS)  // 512 bins: (tr*8+b)*32+band
#define CAP 10240                  // slots/bin; mean ~9.0K

// Workspace layout:
//   [0]      uint  gcount[NBINS]          (2 KB)
//   [4096]   uint2 items[NBINS * CAP]     (42 MB)  (wy_f32, qx<<12|qt<<1|p)

__device__ __forceinline__ float wave_reduce_sum(float v) {
    #pragma unroll
    for (int o = 32; o > 0; o >>= 1) v += __shfl_down(v, o, 64);
    return v;
}

// Pass 1: warp events, bin by (tr, b, 8-row band). Items straddling a band
// boundary are duplicated into both bands.
__global__ __launch_bounds__(256)
void bin_events(const float* __restrict__ flow,
                const float4* __restrict__ ev,
                const float2* __restrict__ pmask,
                unsigned int* __restrict__ gcount,
                uint2* __restrict__ items) {
    __shared__ int lcnt[64];    // local bins: tr*32 + band (b fixed per block)
    __shared__ int lbase[64];
    int tid = threadIdx.x;
    if (tid < 64) lcnt[tid] = 0;
    __syncthreads();

    int bn = blockIdx.x * 256 + tid;
    int b = bn >> NEV_SHIFT;     // uniform across block

    float4 e = ev[bn];           // t, y, x, pol
    float t = e.x, y = e.y, x = e.z;
    float2 m = pmask[bn];
    unsigned int p = (m.x > 0.5f) ? 0u : 1u;

    int iy = (int)y, ix = (int)x;   // exact integers in range
    const float* fb = flow + b * 2 * HWPIX + iy * WW + ix;
    float fx = fb[0];               // channel 0: x-flow
    float fy = fb[HWPIX];           // channel 1: y-flow

    int lbA[2] = {-1, -1}, lbB[2] = {-1, -1};
    int slA[2], slB[2];
    uint2 val[2];

    #pragma unroll
    for (int tr = 0; tr < 2; ++tr) {
        float tref  = tr ? 0.0f : 1.0f;
        float tg    = tr ? (1.0f - t) : t;
        float dtS = (tref - t) * FLOW_SCALING;
        float wy = fmaf(dtS, fy, y);
        float wx = fmaf(dtS, fx, x);
        if (!(wx > -1.0f && wx < (float)WW)) continue;
        if (!(wy > -1.0f && wy < (float)HH)) continue;

        int ty = (int)floorf(wy);
        int band0 = -1, band1 = -1;
        if (ty >= 0 && ty < HH) band0 = ty >> BANDSHIFT;
        int r1 = ty + 1;
        if (r1 >= 0 && r1 < HH) {
            int bb = r1 >> BANDSHIFT;
            if (bb != band0) band1 = bb;
        }

        unsigned int qx = (unsigned int)(fmaf(wx, 2048.0f, 2048.5f)); // round((wx+1)*2048)
        unsigned int qt = (unsigned int)(tg * 2047.0f + 0.5f);
        val[tr] = make_uint2(__float_as_uint(wy), (qx << 12) | (qt << 1) | p);

        if (band0 >= 0) {
            lbA[tr] = tr * BANDS + band0;
            slA[tr] = atomicAdd(&lcnt[lbA[tr]], 1);
        }
        if (band1 >= 0) {
            lbB[tr] = tr * BANDS + band1;
            slB[tr] = atomicAdd(&lcnt[lbB[tr]], 1);
        }
    }
    __syncthreads();

    if (tid < 64) {
        int c = lcnt[tid];
        // gbin = tr*256 + b*32 + band ; tid = tr*32 + band
        int gbin = (tid >> 5) * (BATCH * BANDS) + b * BANDS + (tid & 31);
        lbase[tid] = c > 0 ? (int)atomicAdd(&gcount[gbin], (unsigned int)c) : 0;
    }
    __syncthreads();

    #pragma unroll
    for (int tr = 0; tr < 2; ++tr) {
        if (lbA[tr] >= 0) {
            int lb = lbA[tr];
            int slot = lbase[lb] + slA[tr];
            if (slot < CAP) {
                int gbin = (lb >> 5) * (BATCH * BANDS) + b * BANDS + (lb & 31);
                items[(size_t)gbin * CAP + slot] = val[tr];
            }
        }
        if (lbB[tr] >= 0) {
            int lb = lbB[tr];
            int slot = lbase[lb] + slB[tr];
            if (slot < CAP) {
                int gbin = (lb >> 5) * (BATCH * BANDS) + b * BANDS + (lb & 31);
                items[(size_t)gbin * CAP + slot] = val[tr];
            }
        }
    }
}

// Accumulate one item with ONE ds_add_u32 per corner:
// packed = round(w*1024) | round(w*tg*1024) << 16.
// Per-pixel low-field sum < 2^16 (lambda~12 corner adds, w<=1), so no carry
// into the high field. Rounding is monotone so hi <= lo per add -> its <= iwe.
__device__ __forceinline__ void accum_item(unsigned int* __restrict__ s, int lo,
                                           unsigned int wyu, unsigned int pk) {
    float wy = __uint_as_float(wyu);
    float wx = (float)(pk >> 12) * (1.0f / 2048.0f) - 1.0f;
    float tg = (float)((pk >> 1) & 2047u) * (1.0f / 2047.0f);
    int p = pk & 1u;

    float tyf = floorf(wy);
    float fy = wy - tyf;
    int ty = (int)tyf;
    float lxf = floorf(wx);
    float fxx = wx - lxf;
    int lx = (int)lxf;

    unsigned int* L = s + p * TILEPIX;

    #pragma unroll
    for (int a = 0; a < 2; ++a) {
        int ry = ty + a;
        if ((unsigned)(ry - lo) >= (unsigned)BANDROWS) continue;
        float wrow = a ? fy : (1.0f - fy);
        int rb = (ry - lo) * WW;
        #pragma unroll
        for (int c = 0; c < 2; ++c) {
            int cx = lx + c;
            if ((unsigned)cx >= (unsigned)WW) continue;
            float w = wrow * (c ? fxx : (1.0f - fxx));
            unsigned int lo16 = (unsigned int)fmaf(w, 1024.0f, 0.5f);
            unsigned int hi16 = (unsigned int)fmaf(w * tg, 1024.0f, 0.5f);
            atomicAdd(&L[rb + cx], lo16 | (hi16 << 16));
        }
    }
}

// Pass 2: one block per bin, 1024 threads, 21.5 KB LDS.
// uint4 loads (2 items) + software prefetch. Fused ratio^2 loss.
// ONE global atomic per block.
__global__ __launch_bounds__(1024)
void bin_accum(const unsigned int* __restrict__ gcount,
               const uint2* __restrict__ items,
               float* __restrict__ out) {
    __shared__ unsigned int s[2 * TILEPIX];   // [p][pix] packed (iwe|its) : 21.5 KB
    __shared__ float red[16];

    int band = blockIdx.x;
    int tr   = blockIdx.y;
    int b    = blockIdx.z;
    int tid  = threadIdx.x;

    for (int i = tid; i < 2 * TILEPIX; i += 1024) s[i] = 0u;
    __syncthreads();

    int gbin = (tr * BATCH + b) * BANDS + band;
    int cnt = min((int)gcount[gbin], CAP);
    const uint2* bp = items + (size_t)gbin * CAP;
    const uint4* bp4 = (const uint4*)bp;
    const int lo = band * BANDROWS;

    int npair = cnt >> 1;
    int n = tid;
    uint4 cur = make_uint4(0u, 0u, 0u, 0u);
    if (n < npair) cur = bp4[n];
    while (n < npair) {
        int nn = n + 1024;
        uint4 nxt = make_uint4(0u, 0u, 0u, 0u);
        if (nn < npair) nxt = bp4[nn];
        accum_item(s, lo, cur.x, cur.y);
        accum_item(s, lo, cur.z, cur.w);
        n = nn;
        cur = nxt;
    }
    if ((cnt & 1) && tid == 0) {
        uint2 u = bp[cnt - 1];
        accum_item(s, lo, u.x, u.y);
    }
    __syncthreads();

    // Fused ratio^2 loss. Counts are (iwe*1024, its*1024); the 1024 scale
    // cancels in the ratio: r = its_cnt / (iwe_cnt + 1024e-9).
    float v = 0.0f;
    for (int i = tid; i < 2 * TILEPIX; i += 1024) {
        unsigned int u = s[i];
        float iwe = (float)(u & 0xffffu);
        float its = (float)(u >> 16);
        float r = its / (iwe + 1.024e-6f);
        v += r * r;
    }
    v = wave_reduce_sum(v);
    if ((tid & 63) == 0) red[tid >> 6] = v;
    __syncthreads();
    if (tid < 16) {
        float r = red[tid];
        r += __shfl_down(r, 8, 64);
        r += __shfl_down(r, 4, 64);
        r += __shfl_down(r, 2, 64);
        r += __shfl_down(r, 1, 64);
        if (tid == 0) atomicAdd(out, r);
    }
}

__global__ __launch_bounds__(256)
void smooth_loss(const float* __restrict__ flow, float* __restrict__ out) {
    __shared__ float red[4];
    const int TOT = BATCH * 2 * HWPIX;
    float v = 0.0f;
    for (int i = blockIdx.x * blockDim.x + threadIdx.x; i < TOT;
         i += gridDim.x * blockDim.x) {
        int pix = i % HWPIX;
        int col = pix % WW;
        int row = pix / WW;
        float f = flow[i];
        if (row < HH - 1) {
            float d = f - flow[i + WW];
            v += sqrtf(d * d + 1e-6f);
        }
        if (col < WW - 1) {
            float d = f - flow[i + 1];
            v += sqrtf(d * d + 1e-6f);
        }
    }
    int tid = threadIdx.x;
    v = wave_reduce_sum(v);
    if ((tid & 63) == 0) red[tid >> 6] = v;
    __syncthreads();
    if (tid < 4) {
        float r = red[tid];
        r += __shfl_down(r, 2, 64);
        r += __shfl_down(r, 1, 64);
        if (tid == 0) atomicAdd(out, REG_WEIGHT * r);
    }
}

extern "C" void kernel_launch(void* const* d_in, const int* in_sizes, int n_in,
                              void* d_out, int out_size, void* d_ws, size_t ws_size,
                              hipStream_t stream) {
    const float*  flow  = (const float*)d_in[0];
    const float4* ev    = (const float4*)d_in[1];
    const float2* pmask = (const float2*)d_in[2];
    float* out = (float*)d_out;

    unsigned int* gcount = (unsigned int*)d_ws;
    uint2* items = (uint2*)((char*)d_ws + 4096);

    hipMemsetAsync(gcount, 0, NBINS * sizeof(unsigned int), stream);
    hipMemsetAsync(d_out, 0, sizeof(float), stream);

    int total_ev = BATCH * NEV;
    bin_events<<<total_ev / 256, 256, 0, stream>>>(flow, ev, pmask, gcount, items);

    dim3 g2(BANDS, 2, BATCH);
    bin_accum<<<g2, 1024, 0, stream>>>(gcount, items, out);

    smooth_loss<<<256, 256, 0, stream>>>(flow, out);
}

// Round 7
// 197.044 us; speedup vs baseline: 2.2086x; 1.0041x over previous
//
#include <hip/hip_runtime.h>

// Problem constants (from reference)
#define HH 256
#define WW 336
#define HWPIX (HH * WW)          // 86016
#define BATCH 8
#define NEV 262144               // 2^18
#define NEV_SHIFT 18
#define FLOW_SCALING 336.0f
#define REG_WEIGHT 0.001f

#define BANDS 32
#define BANDSHIFT 3
#define BANDROWS 8
#define TILEPIX (BANDROWS * WW)    // 2688
#define NBINS (2 * BATCH * BANDS)  // 512 bins: (tr*8+b)*32+band
#define CAP 10240                  // slots/bin; mean ~9.0K

// Workspace layout:
//   [0]        uint   gcount[NBINS]          (2 KB)
//   [4096]     uint2  items[NBINS * CAP]     (42 MB)  (wy_f32, qx<<12|qt<<1|p)
//   [after]    float2 flowi[BATCH * HWPIX]   (5.5 MB) interleaved (fx, fy)
#define ITEMS_BYTES ((size_t)NBINS * CAP * 8)

__device__ __forceinline__ float wave_reduce_sum(float v) {
    #pragma unroll
    for (int o = 32; o > 0; o >>= 1) v += __shfl_down(v, o, 64);
    return v;
}

// Pre-pass: interleave flow channels so the per-event gather is one 8B load.
__global__ __launch_bounds__(256)
void flow_interleave(const float* __restrict__ flow, float2* __restrict__ flowi) {
    int i = blockIdx.x * 256 + threadIdx.x;
    if (i >= BATCH * HWPIX) return;
    int b = i / HWPIX, pix = i - b * HWPIX;
    const float* fb = flow + (size_t)b * 2 * HWPIX;
    flowi[i] = make_float2(fb[pix], fb[HWPIX + pix]);
}

// Pass 1: warp events, bin by (tr, b, 8-row band); straddling items duplicated.
// Items are staged in LDS ordered by local bin, then flushed with consecutive
// threads writing consecutive global slots (wave-coalesced stores).
#define MAXITEMS 1024   // worst case 4 copies per thread * 256
__global__ __launch_bounds__(256)
void bin_events(const float2* __restrict__ flowi,
                const float4* __restrict__ ev,
                unsigned int* __restrict__ gcount,
                uint2* __restrict__ items) {
    __shared__ int lcnt[64];     // local bins: tr*32 + band (b fixed per block)
    __shared__ int loff[64];     // exclusive prefix (LDS staging offset)
    __shared__ int gbase[64];    // global slot base per local bin
    __shared__ int stotal;
    __shared__ uint2 sval[MAXITEMS];
    __shared__ unsigned int sgs[MAXITEMS];   // global slot index (~0 = skip)

    int tid = threadIdx.x;
    if (tid < 64) lcnt[tid] = 0;
    __syncthreads();

    int bn = blockIdx.x * 256 + tid;
    int b = bn >> NEV_SHIFT;     // uniform across block

    float4 e = ev[bn];           // t, y, x, pol(+/-1)
    float t = e.x, y = e.y, x = e.z;
    unsigned int p = (e.w > 0.0f) ? 0u : 1u;   // p=0 <-> pol==+1

    int iy = (int)y, ix = (int)x;   // exact integers in range
    float2 f = flowi[b * HWPIX + iy * WW + ix];
    float fx = f.x, fy = f.y;

    int lbA[2] = {-1, -1}, lbB[2] = {-1, -1};
    int slA[2], slB[2];
    uint2 val[2];

    #pragma unroll
    for (int tr = 0; tr < 2; ++tr) {
        float tref  = tr ? 0.0f : 1.0f;
        float tg    = tr ? (1.0f - t) : t;
        float dtS = (tref - t) * FLOW_SCALING;
        float wy = fmaf(dtS, fy, y);
        float wx = fmaf(dtS, fx, x);
        if (!(wx > -1.0f && wx < (float)WW)) continue;
        if (!(wy > -1.0f && wy < (float)HH)) continue;

        int ty = (int)floorf(wy);
        int band0 = -1, band1 = -1;
        if (ty >= 0 && ty < HH) band0 = ty >> BANDSHIFT;
        int r1 = ty + 1;
        if (r1 >= 0 && r1 < HH) {
            int bb = r1 >> BANDSHIFT;
            if (bb != band0) band1 = bb;
        }

        unsigned int qx = (unsigned int)(fmaf(wx, 2048.0f, 2048.5f)); // round((wx+1)*2048)
        unsigned int qt = (unsigned int)(tg * 2047.0f + 0.5f);
        val[tr] = make_uint2(__float_as_uint(wy), (qx << 12) | (qt << 1) | p);

        if (band0 >= 0) {
            lbA[tr] = tr * BANDS + band0;
            slA[tr] = atomicAdd(&lcnt[lbA[tr]], 1);
        }
        if (band1 >= 0) {
            lbB[tr] = tr * BANDS + band1;
            slB[tr] = atomicAdd(&lcnt[lbB[tr]], 1);
        }
    }
    __syncthreads();

    if (tid < 64) {
        int c = lcnt[tid];
        // wave-wide inclusive scan over the 64 counters
        int xg = c;
        #pragma unroll
        for (int o = 1; o < 64; o <<= 1) {
            int yv = __shfl_up(xg, o, 64);
            if (tid >= o) xg += yv;
        }
        loff[tid] = xg - c;             // exclusive prefix
        if (tid == 63) stotal = xg;
        // gbin = tr*256 + b*32 + band ; tid = tr*32 + band
        int gbin = (tid >> 5) * (BATCH * BANDS) + b * BANDS + (tid & 31);
        gbase[tid] = c > 0 ? (int)atomicAdd(&gcount[gbin], (unsigned int)c) : 0;
    }
    __syncthreads();

    #pragma unroll
    for (int tr = 0; tr < 2; ++tr) {
        if (lbA[tr] >= 0) {
            int lb = lbA[tr];
            int pos = loff[lb] + slA[tr];
            int gs = gbase[lb] + slA[tr];
            int gbin = (lb >> 5) * (BATCH * BANDS) + b * BANDS + (lb & 31);
            sval[pos] = val[tr];
            sgs[pos] = (gs < CAP) ? (unsigned int)(gbin * CAP + gs) : 0xffffffffu;
        }
        if (lbB[tr] >= 0) {
            int lb = lbB[tr];
            int pos = loff[lb] + slB[tr];
            int gs = gbase[lb] + slB[tr];
            int gbin = (lb >> 5) * (BATCH * BANDS) + b * BANDS + (lb & 31);
            sval[pos] = val[tr];
            sgs[pos] = (gs < CAP) ? (unsigned int)(gbin * CAP + gs) : 0xffffffffu;
        }
    }
    __syncthreads();

    int total = stotal;
    for (int i = tid; i < total; i += 256) {
        unsigned int g = sgs[i];
        if (g != 0xffffffffu) items[g] = sval[i];
    }
}

// Accumulate one item with ONE ds_add_u32 per corner:
// packed = round(w*1024) | round(w*tg*1024) << 16.
// Per-pixel low-field sum < 2^16 (lambda~12 corner adds, w<=1), so no carry
// into the high field. Rounding is monotone so hi <= lo per add -> its <= iwe.
__device__ __forceinline__ void accum_item(unsigned int* __restrict__ s, int lo,
                                           unsigned int wyu, unsigned int pk) {
    float wy = __uint_as_float(wyu);
    float wx = (float)(pk >> 12) * (1.0f / 2048.0f) - 1.0f;
    float tg = (float)((pk >> 1) & 2047u) * (1.0f / 2047.0f);
    int p = pk & 1u;

    float tyf = floorf(wy);
    float fy = wy - tyf;
    int ty = (int)tyf;
    float lxf = floorf(wx);
    float fxx = wx - lxf;
    int lx = (int)lxf;

    unsigned int* L = s + p * TILEPIX;

    #pragma unroll
    for (int a = 0; a < 2; ++a) {
        int ry = ty + a;
        if ((unsigned)(ry - lo) >= (unsigned)BANDROWS) continue;
        float wrow = a ? fy : (1.0f - fy);
        int rb = (ry - lo) * WW;
        #pragma unroll
        for (int c = 0; c < 2; ++c) {
            int cx = lx + c;
            if ((unsigned)cx >= (unsigned)WW) continue;
            float w = wrow * (c ? fxx : (1.0f - fxx));
            unsigned int lo16 = (unsigned int)fmaf(w, 1024.0f, 0.5f);
            unsigned int hi16 = (unsigned int)fmaf(w * tg, 1024.0f, 0.5f);
            atomicAdd(&L[rb + cx], lo16 | (hi16 << 16));
        }
    }
}

// Pass 2: one block per bin, 1024 threads, 21.5 KB LDS.
// uint4 loads (2 items) + software prefetch. Fused ratio^2 loss.
// ONE global atomic per block.
__global__ __launch_bounds__(1024)
void bin_accum(const unsigned int* __restrict__ gcount,
               const uint2* __restrict__ items,
               float* __restrict__ out) {
    __shared__ unsigned int s[2 * TILEPIX];   // [p][pix] packed (iwe|its) : 21.5 KB
    __shared__ float red[16];

    int band = blockIdx.x;
    int tr   = blockIdx.y;
    int b    = blockIdx.z;
    int tid  = threadIdx.x;

    for (int i = tid; i < 2 * TILEPIX; i += 1024) s[i] = 0u;
    __syncthreads();

    int gbin = (tr * BATCH + b) * BANDS + band;
    int cnt = min((int)gcount[gbin], CAP);
    const uint2* bp = items + (size_t)gbin * CAP;
    const uint4* bp4 = (const uint4*)bp;
    const int lo = band * BANDROWS;

    int npair = cnt >> 1;
    int n = tid;
    uint4 cur = make_uint4(0u, 0u, 0u, 0u);
    if (n < npair) cur = bp4[n];
    while (n < npair) {
        int nn = n + 1024;
        uint4 nxt = make_uint4(0u, 0u, 0u, 0u);
        if (nn < npair) nxt = bp4[nn];
        accum_item(s, lo, cur.x, cur.y);
        accum_item(s, lo, cur.z, cur.w);
        n = nn;
        cur = nxt;
    }
    if ((cnt & 1) && tid == 0) {
        uint2 u = bp[cnt - 1];
        accum_item(s, lo, u.x, u.y);
    }
    __syncthreads();

    // Fused ratio^2 loss. Counts are (iwe*1024, its*1024); scale cancels.
    float v = 0.0f;
    for (int i = tid; i < 2 * TILEPIX; i += 1024) {
        unsigned int u = s[i];
        float iwe = (float)(u & 0xffffu);
        float its = (float)(u >> 16);
        float r = its / (iwe + 1.024e-6f);
        v += r * r;
    }
    v = wave_reduce_sum(v);
    if ((tid & 63) == 0) red[tid >> 6] = v;
    __syncthreads();
    if (tid < 16) {
        float r = red[tid];
        r += __shfl_down(r, 8, 64);
        r += __shfl_down(r, 4, 64);
        r += __shfl_down(r, 2, 64);
        r += __shfl_down(r, 1, 64);
        if (tid == 0) atomicAdd(out, r);
    }
}

__global__ __launch_bounds__(256)
void smooth_loss(const float* __restrict__ flow, float* __restrict__ out) {
    __shared__ float red[4];
    const int TOT = BATCH * 2 * HWPIX;
    float v = 0.0f;
    for (int i = blockIdx.x * blockDim.x + threadIdx.x; i < TOT;
         i += gridDim.x * blockDim.x) {
        int pix = i % HWPIX;
        int col = pix % WW;
        int row = pix / WW;
        float f = flow[i];
        if (row < HH - 1) {
            float d = f - flow[i + WW];
            v += sqrtf(d * d + 1e-6f);
        }
        if (col < WW - 1) {
            float d = f - flow[i + 1];
            v += sqrtf(d * d + 1e-6f);
        }
    }
    int tid = threadIdx.x;
    v = wave_reduce_sum(v);
    if ((tid & 63) == 0) red[tid >> 6] = v;
    __syncthreads();
    if (tid < 4) {
        float r = red[tid];
        r += __shfl_down(r, 2, 64);
        r += __shfl_down(r, 1, 64);
        if (tid == 0) atomicAdd(out, REG_WEIGHT * r);
    }
}

extern "C" void kernel_launch(void* const* d_in, const int* in_sizes, int n_in,
                              void* d_out, int out_size, void* d_ws, size_t ws_size,
                              hipStream_t stream) {
    const float*  flow  = (const float*)d_in[0];
    const float4* ev    = (const float4*)d_in[1];
    float* out = (float*)d_out;

    unsigned int* gcount = (unsigned int*)d_ws;
    uint2* items = (uint2*)((char*)d_ws + 4096);
    float2* flowi = (float2*)((char*)d_ws + 4096 + ITEMS_BYTES);

    hipMemsetAsync(gcount, 0, NBINS * sizeof(unsigned int), stream);
    hipMemsetAsync(d_out, 0, sizeof(float), stream);

    flow_interleave<<<(BATCH * HWPIX + 255) / 256, 256, 0, stream>>>(flow, flowi);

    int total_ev = BATCH * NEV;
    bin_events<<<total_ev / 256, 256, 0, stream>>>(flowi, ev, gcount, items);

    dim3 g2(BANDS, 2, BATCH);
    bin_accum<<<g2, 1024, 0, stream>>>(gcount, items, out);

    smooth_loss<<<256, 256, 0, stream>>>(flow, out);
}

// Round 8
// 190.825 us; speedup vs baseline: 2.2806x; 1.0326x over previous
//
#include <hip/hip_runtime.h>

// Problem constants (from reference)
#define HH 256
#define WW 336
#define HWPIX (HH * WW)          // 86016
#define BATCH 8
#define NEV 262144               // 2^18
#define NEV_SHIFT 18
#define FLOW_SCALING 336.0f
#define REG_WEIGHT 0.001f

#define BANDS 32
#define BANDSHIFT 3
#define BANDROWS 8
#define TILEPIX (BANDROWS * WW)    // 2688
#define NBINS (2 * BATCH * BANDS)  // 512 bins: (tr*8+b)*32+band
#define CAP 10240                  // slots/bin; mean ~9.0K

// Workspace layout:
//   [0]        uint   gcount[NBINS]          (2 KB)
//   [4096]     uint2  items[NBINS * CAP]     (42 MB)  (wy_f32, qx<<12|qt<<1|p)
//   [after]    float2 flowi[BATCH * HWPIX]   (5.5 MB) interleaved (fx, fy)
#define ITEMS_BYTES ((size_t)NBINS * CAP * 8)

__device__ __forceinline__ float wave_reduce_sum(float v) {
    #pragma unroll
    for (int o = 32; o > 0; o >>= 1) v += __shfl_down(v, o, 64);
    return v;
}

// Pre-pass: interleave flow channels (for the per-event 8B gather) FUSED with
// the Charbonnier smoothness loss (flow is read exactly once).
__global__ __launch_bounds__(256)
void flow_prep(const float* __restrict__ flow, float2* __restrict__ flowi,
               float* __restrict__ out) {
    __shared__ float red[4];
    float v = 0.0f;
    for (int i = blockIdx.x * 256 + threadIdx.x; i < BATCH * HWPIX;
         i += gridDim.x * 256) {
        int b = i / HWPIX, pix = i - b * HWPIX;
        const float* fb = flow + (size_t)b * 2 * HWPIX;
        float fxv = fb[pix];
        float fyv = fb[HWPIX + pix];
        flowi[i] = make_float2(fxv, fyv);
        int col = pix % WW, row = pix / WW;
        if (row < HH - 1) {
            float d0 = fxv - fb[pix + WW];
            float d1 = fyv - fb[HWPIX + pix + WW];
            v += sqrtf(d0 * d0 + 1e-6f) + sqrtf(d1 * d1 + 1e-6f);
        }
        if (col < WW - 1) {
            float d0 = fxv - fb[pix + 1];
            float d1 = fyv - fb[HWPIX + pix + 1];
            v += sqrtf(d0 * d0 + 1e-6f) + sqrtf(d1 * d1 + 1e-6f);
        }
    }
    int tid = threadIdx.x;
    v = wave_reduce_sum(v);
    if ((tid & 63) == 0) red[tid >> 6] = v;
    __syncthreads();
    if (tid < 4) {
        float r = red[tid];
        r += __shfl_down(r, 2, 64);
        r += __shfl_down(r, 1, 64);
        if (tid == 0) atomicAdd(out, REG_WEIGHT * r);
    }
}

// Pass 1: warp events, bin by (tr, b, 8-row band); straddling items duplicated.
// Items staged in LDS ordered by local bin, flushed wave-coalesced with
// nontemporal stores (stream-once data: skip write-allocate).
#define MAXITEMS 1024   // worst case 4 copies per thread * 256
__global__ __launch_bounds__(256)
void bin_events(const float2* __restrict__ flowi,
                const float4* __restrict__ ev,
                unsigned int* __restrict__ gcount,
                uint2* __restrict__ items) {
    __shared__ int lcnt[64];     // local bins: tr*32 + band (b fixed per block)
    __shared__ int loff[64];     // exclusive prefix (LDS staging offset)
    __shared__ int gbase[64];    // global slot base per local bin
    __shared__ int stotal;
    __shared__ uint2 sval[MAXITEMS];
    __shared__ unsigned int sgs[MAXITEMS];   // global slot index (~0 = skip)

    int tid = threadIdx.x;
    if (tid < 64) lcnt[tid] = 0;
    __syncthreads();

    int bn = blockIdx.x * 256 + tid;
    int b = bn >> NEV_SHIFT;     // uniform across block

    float4 e = ev[bn];           // t, y, x, pol(+/-1)
    float t = e.x, y = e.y, x = e.z;
    unsigned int p = (e.w > 0.0f) ? 0u : 1u;   // p=0 <-> pol==+1

    int iy = (int)y, ix = (int)x;   // exact integers in range
    float2 f = flowi[b * HWPIX + iy * WW + ix];
    float fx = f.x, fy = f.y;

    int lbA[2] = {-1, -1}, lbB[2] = {-1, -1};
    int slA[2], slB[2];
    uint2 val[2];

    #pragma unroll
    for (int tr = 0; tr < 2; ++tr) {
        float tref  = tr ? 0.0f : 1.0f;
        float tg    = tr ? (1.0f - t) : t;
        float dtS = (tref - t) * FLOW_SCALING;
        float wy = fmaf(dtS, fy, y);
        float wx = fmaf(dtS, fx, x);
        if (!(wx > -1.0f && wx < (float)WW)) continue;
        if (!(wy > -1.0f && wy < (float)HH)) continue;

        int ty = (int)floorf(wy);
        int band0 = -1, band1 = -1;
        if (ty >= 0 && ty < HH) band0 = ty >> BANDSHIFT;
        int r1 = ty + 1;
        if (r1 >= 0 && r1 < HH) {
            int bb = r1 >> BANDSHIFT;
            if (bb != band0) band1 = bb;
        }

        unsigned int qx = (unsigned int)(fmaf(wx, 2048.0f, 2048.5f)); // round((wx+1)*2048)
        unsigned int qt = (unsigned int)(tg * 2047.0f + 0.5f);
        val[tr] = make_uint2(__float_as_uint(wy), (qx << 12) | (qt << 1) | p);

        if (band0 >= 0) {
            lbA[tr] = tr * BANDS + band0;
            slA[tr] = atomicAdd(&lcnt[lbA[tr]], 1);
        }
        if (band1 >= 0) {
            lbB[tr] = tr * BANDS + band1;
            slB[tr] = atomicAdd(&lcnt[lbB[tr]], 1);
        }
    }
    __syncthreads();

    if (tid < 64) {
        int c = lcnt[tid];
        // wave-wide inclusive scan over the 64 counters
        int xg = c;
        #pragma unroll
        for (int o = 1; o < 64; o <<= 1) {
            int yv = __shfl_up(xg, o, 64);
            if (tid >= o) xg += yv;
        }
        loff[tid] = xg - c;             // exclusive prefix
        if (tid == 63) stotal = xg;
        // gbin = tr*256 + b*32 + band ; tid = tr*32 + band
        int gbin = (tid >> 5) * (BATCH * BANDS) + b * BANDS + (tid & 31);
        gbase[tid] = c > 0 ? (int)atomicAdd(&gcount[gbin], (unsigned int)c) : 0;
    }
    __syncthreads();

    #pragma unroll
    for (int tr = 0; tr < 2; ++tr) {
        if (lbA[tr] >= 0) {
            int lb = lbA[tr];
            int pos = loff[lb] + slA[tr];
            int gs = gbase[lb] + slA[tr];
            int gbin = (lb >> 5) * (BATCH * BANDS) + b * BANDS + (lb & 31);
            sval[pos] = val[tr];
            sgs[pos] = (gs < CAP) ? (unsigned int)(gbin * CAP + gs) : 0xffffffffu;
        }
        if (lbB[tr] >= 0) {
            int lb = lbB[tr];
            int pos = loff[lb] + slB[tr];
            int gs = gbase[lb] + slB[tr];
            int gbin = (lb >> 5) * (BATCH * BANDS) + b * BANDS + (lb & 31);
            sval[pos] = val[tr];
            sgs[pos] = (gs < CAP) ? (unsigned int)(gbin * CAP + gs) : 0xffffffffu;
        }
    }
    __syncthreads();

    int total = stotal;
    for (int i = tid; i < total; i += 256) {
        unsigned int g = sgs[i];
        if (g != 0xffffffffu) {
            uint2 vv = sval[i];
            unsigned long long packed =
                (unsigned long long)vv.x | ((unsigned long long)vv.y << 32);
            __builtin_nontemporal_store(packed, (unsigned long long*)&items[g]);
        }
    }
}

__device__ __forceinline__ unsigned int pack_w(float w, float tg) {
    unsigned int lo16 = (unsigned int)fmaf(w, 1024.0f, 0.5f);
    unsigned int hi16 = (unsigned int)fmaf(w * tg, 1024.0f, 0.5f);
    return lo16 | (hi16 << 16);
}

// Accumulate one item. Corner adds are packed (w,w*tg) u32 counts; when the
// (left,right) pair is interior and 8B-aligned (even lx), ONE ds_add_u64
// covers both corners. No carry crosses the 32-bit boundary because each
// 16-bit field's per-pixel sum stays < 2^16 (lambda ~12 adds/pixel, w<=1).
__device__ __forceinline__ void accum_item(unsigned int* __restrict__ s, int lo,
                                           unsigned int wyu, unsigned int pk) {
    float wy = __uint_as_float(wyu);
    float wx = (float)(pk >> 12) * (1.0f / 2048.0f) - 1.0f;
    float tg = (float)((pk >> 1) & 2047u) * (1.0f / 2047.0f);
    int p = pk & 1u;

    float tyf = floorf(wy);
    float fy = wy - tyf;
    int ty = (int)tyf;
    float lxf = floorf(wx);
    float fxx = wx - lxf;
    int lx = (int)lxf;

    unsigned int* L = s + p * TILEPIX;

    #pragma unroll
    for (int a = 0; a < 2; ++a) {
        int ry = ty + a;
        if ((unsigned)(ry - lo) >= (unsigned)BANDROWS) continue;
        float wrow = a ? fy : (1.0f - fy);
        int rb = (ry - lo) * WW;
        if (lx >= 0 && lx + 1 < WW) {
            unsigned int pl = pack_w(wrow * (1.0f - fxx), tg);
            unsigned int pr = pack_w(wrow * fxx, tg);
            if ((lx & 1) == 0) {
                unsigned long long v =
                    (unsigned long long)pl | ((unsigned long long)pr << 32);
                atomicAdd((unsigned long long*)(L + rb + lx), v);
            } else {
                atomicAdd(&L[rb + lx], pl);
                atomicAdd(&L[rb + lx + 1], pr);
            }
        } else if (lx == -1) {
            atomicAdd(&L[rb], pack_w(wrow * fxx, tg));
        } else if (lx == WW - 1) {
            atomicAdd(&L[rb + lx], pack_w(wrow * (1.0f - fxx), tg));
        }
    }
}

// Pass 2: one block per bin, 1024 threads, 21.5 KB LDS.
// uint4 loads (2 items) + software prefetch. Fused ratio^2 loss.
// ONE global atomic per block.
__global__ __launch_bounds__(1024)
void bin_accum(const unsigned int* __restrict__ gcount,
               const uint2* __restrict__ items,
               float* __restrict__ out) {
    __shared__ __align__(8) unsigned int s[2 * TILEPIX];  // [p][pix] packed : 21.5 KB
    __shared__ float red[16];

    int band = blockIdx.x;
    int tr   = blockIdx.y;
    int b    = blockIdx.z;
    int tid  = threadIdx.x;

    for (int i = tid; i < 2 * TILEPIX; i += 1024) s[i] = 0u;
    __syncthreads();

    int gbin = (tr * BATCH + b) * BANDS + band;
    int cnt = min((int)gcount[gbin], CAP);
    const uint2* bp = items + (size_t)gbin * CAP;
    const uint4* bp4 = (const uint4*)bp;
    const int lo = band * BANDROWS;

    int npair = cnt >> 1;
    int n = tid;
    uint4 cur = make_uint4(0u, 0u, 0u, 0u);
    if (n < npair) cur = bp4[n];
    while (n < npair) {
        int nn = n + 1024;
        uint4 nxt = make_uint4(0u, 0u, 0u, 0u);
        if (nn < npair) nxt = bp4[nn];
        accum_item(s, lo, cur.x, cur.y);
        accum_item(s, lo, cur.z, cur.w);
        n = nn;
        cur = nxt;
    }
    if ((cnt & 1) && tid == 0) {
        uint2 u = bp[cnt - 1];
        accum_item(s, lo, u.x, u.y);
    }
    __syncthreads();

    // Fused ratio^2 loss. Counts are (iwe*1024, its*1024); scale cancels.
    float v = 0.0f;
    for (int i = tid; i < 2 * TILEPIX; i += 1024) {
        unsigned int u = s[i];
        float iwe = (float)(u & 0xffffu);
        float its = (float)(u >> 16);
        float r = its / (iwe + 1.024e-6f);
        v += r * r;
    }
    v = wave_reduce_sum(v);
    if ((tid & 63) == 0) red[tid >> 6] = v;
    __syncthreads();
    if (tid < 16) {
        float r = red[tid];
        r += __shfl_down(r, 8, 64);
        r += __shfl_down(r, 4, 64);
        r += __shfl_down(r, 2, 64);
        r += __shfl_down(r, 1, 64);
        if (tid == 0) atomicAdd(out, r);
    }
}

extern "C" void kernel_launch(void* const* d_in, const int* in_sizes, int n_in,
                              void* d_out, int out_size, void* d_ws, size_t ws_size,
                              hipStream_t stream) {
    const float*  flow  = (const float*)d_in[0];
    const float4* ev    = (const float4*)d_in[1];
    float* out = (float*)d_out;

    unsigned int* gcount = (unsigned int*)d_ws;
    uint2* items = (uint2*)((char*)d_ws + 4096);
    float2* flowi = (float2*)((char*)d_ws + 4096 + ITEMS_BYTES);

    hipMemsetAsync(gcount, 0, NBINS * sizeof(unsigned int), stream);
    hipMemsetAsync(d_out, 0, sizeof(float), stream);

    flow_prep<<<512, 256, 0, stream>>>(flow, flowi, out);

    int total_ev = BATCH * NEV;
    bin_events<<<total_ev / 256, 256, 0, stream>>>(flowi, ev, gcount, items);

    dim3 g2(BANDS, 2, BATCH);
    bin_accum<<<g2, 1024, 0, stream>>>(gcount, items, out);
}

// Round 9
// 172.944 us; speedup vs baseline: 2.5164x; 1.1034x over previous
//
#include <hip/hip_runtime.h>

// Problem constants (from reference)
#define HH 256
#define WW 336
#define HWPIX (HH * WW)          // 86016
#define BATCH 8
#define NEV 262144               // 2^18
#define NEV_SHIFT 18
#define FLOW_SCALING 336.0f
#define REG_WEIGHT 0.001f

#define BANDS 16
#define BANDSHIFT 4
#define BANDROWS 16
#define TILEPIX (BANDROWS * WW)    // 5376
#define NBINS (2 * BATCH * BANDS)  // 256 bins: (tr*8+b)*16+band
#define CAP 20480                  // slots/bin; mean ~16.5K

// Workspace layout:
//   [0]        uint   gcount[NBINS]          (1 KB)
//   [4096]     uint2  items[NBINS * CAP]     (40 MB)  (pk, qy16)
//   [after]    float2 flowi[BATCH * HWPIX]   (5.5 MB) interleaved (fx, fy)
// item.x = pk  = qx<<12 | qt<<1 | p     (qx = round((wx+1)*2048), 20 bits)
// item.y = qy  = round((wy - band*16 + 1) * 2048), 16 bits (band-relative)
#define ITEMS_BYTES ((size_t)NBINS * CAP * 8)

__device__ __forceinline__ float wave_reduce_sum(float v) {
    #pragma unroll
    for (int o = 32; o > 0; o >>= 1) v += __shfl_down(v, o, 64);
    return v;
}

// Pre-pass: interleave flow channels (for the per-event 8B gather) FUSED with
// the Charbonnier smoothness loss (flow is read exactly once).
__global__ __launch_bounds__(256)
void flow_prep(const float* __restrict__ flow, float2* __restrict__ flowi,
               float* __restrict__ out) {
    __shared__ float red[4];
    float v = 0.0f;
    for (int i = blockIdx.x * 256 + threadIdx.x; i < BATCH * HWPIX;
         i += gridDim.x * 256) {
        int b = i / HWPIX, pix = i - b * HWPIX;
        const float* fb = flow + (size_t)b * 2 * HWPIX;
        float fxv = fb[pix];
        float fyv = fb[HWPIX + pix];
        flowi[i] = make_float2(fxv, fyv);
        int col = pix % WW, row = pix / WW;
        if (row < HH - 1) {
            float d0 = fxv - fb[pix + WW];
            float d1 = fyv - fb[HWPIX + pix + WW];
            v += sqrtf(d0 * d0 + 1e-6f) + sqrtf(d1 * d1 + 1e-6f);
        }
        if (col < WW - 1) {
            float d0 = fxv - fb[pix + 1];
            float d1 = fyv - fb[HWPIX + pix + 1];
            v += sqrtf(d0 * d0 + 1e-6f) + sqrtf(d1 * d1 + 1e-6f);
        }
    }
    int tid = threadIdx.x;
    v = wave_reduce_sum(v);
    if ((tid & 63) == 0) red[tid >> 6] = v;
    __syncthreads();
    if (tid < 4) {
        float r = red[tid];
        r += __shfl_down(r, 2, 64);
        r += __shfl_down(r, 1, 64);
        if (tid == 0) atomicAdd(out, REG_WEIGHT * r);
    }
}

// Pass 1: warp events, bin by (tr, b, 16-row band); straddling items duplicated
// into both bands. Staged items carry (qy16 | lb<<16 | rank<<21) in the high
// word, so no separate slot array is needed: flush recomputes the global slot
// as gbase[lb] + rank.  3 LDS ops/item instead of 4.
#define MAXITEMS 1024   // worst case 4 copies per thread... <=1024 per block
__global__ __launch_bounds__(256)
void bin_events(const float2* __restrict__ flowi,
                const float4* __restrict__ ev,
                unsigned int* __restrict__ gcount,
                uint2* __restrict__ items) {
    __shared__ int lcnt[32];     // local bins: tr*16 + band (b fixed per block)
    __shared__ int loff[32];     // exclusive prefix (LDS staging offset)
    __shared__ int gbase[32];    // global slot base per local bin
    __shared__ int stotal;
    __shared__ unsigned long long sval[MAXITEMS];

    int tid = threadIdx.x;
    if (tid < 32) lcnt[tid] = 0;
    __syncthreads();

    int bn = blockIdx.x * 256 + tid;
    int b = bn >> NEV_SHIFT;     // uniform across block

    float4 e = ev[bn];           // t, y, x, pol(+/-1)
    float t = e.x, y = e.y, x = e.z;
    unsigned int p = (e.w > 0.0f) ? 0u : 1u;   // p=0 <-> pol==+1

    int iy = (int)y, ix = (int)x;   // exact integers in range
    float2 f = flowi[b * HWPIX + iy * WW + ix];
    float fx = f.x, fy = f.y;

    int lbA[2] = {-1, -1}, lbB[2] = {-1, -1};
    int slA[2], slB[2];
    unsigned int qyA[2], qyB[2], pkv[2];

    #pragma unroll
    for (int tr = 0; tr < 2; ++tr) {
        float tref  = tr ? 0.0f : 1.0f;
        float tg    = tr ? (1.0f - t) : t;
        float dtS = (tref - t) * FLOW_SCALING;
        float wy = fmaf(dtS, fy, y);
        float wx = fmaf(dtS, fx, x);
        if (!(wx > -1.0f && wx < (float)WW)) continue;
        if (!(wy > -1.0f && wy < (float)HH)) continue;

        int ty = (int)floorf(wy);
        int band0 = -1, band1 = -1;
        if (ty >= 0 && ty < HH) band0 = ty >> BANDSHIFT;
        int r1 = ty + 1;
        if (r1 >= 0 && r1 < HH) {
            int bb = r1 >> BANDSHIFT;
            if (bb != band0) band1 = bb;
        }

        unsigned int qx = (unsigned int)(fmaf(wx, 2048.0f, 2048.5f)); // round((wx+1)*2048)
        unsigned int qt = (unsigned int)(tg * 2047.0f + 0.5f);
        pkv[tr] = (qx << 12) | (qt << 1) | p;

        if (band0 >= 0) {
            float wyrel = wy - (float)(band0 * BANDROWS - 1);   // [1, 17)
            qyA[tr] = (unsigned int)fmaf(wyrel, 2048.0f, 0.5f); // 16 bits
            lbA[tr] = tr * BANDS + band0;
            slA[tr] = atomicAdd(&lcnt[lbA[tr]], 1);
        }
        if (band1 >= 0) {
            float wyrel = wy - (float)(band1 * BANDROWS - 1);   // [0, 1)
            qyB[tr] = (unsigned int)fmaf(wyrel, 2048.0f, 0.5f);
            lbB[tr] = tr * BANDS + band1;
            slB[tr] = atomicAdd(&lcnt[lbB[tr]], 1);
        }
    }
    __syncthreads();

    if (tid < 32) {
        int c = lcnt[tid];
        // wave-wide inclusive scan over the 32 counters (lanes 0..31)
        int xg = c;
        #pragma unroll
        for (int o = 1; o < 32; o <<= 1) {
            int yv = __shfl_up(xg, o, 64);
            if (tid >= o) xg += yv;
        }
        loff[tid] = xg - c;             // exclusive prefix
        if (tid == 31) stotal = xg;
        // gbin = tr*128 + b*16 + band ; tid = tr*16 + band
        int gbin = (tid >> 4) * (BATCH * BANDS) + b * BANDS + (tid & 15);
        gbase[tid] = c > 0 ? (int)atomicAdd(&gcount[gbin], (unsigned int)c) : 0;
    }
    __syncthreads();

    #pragma unroll
    for (int tr = 0; tr < 2; ++tr) {
        if (lbA[tr] >= 0) {
            int lb = lbA[tr], rank = slA[tr];
            unsigned int hi = qyA[tr] | ((unsigned int)lb << 16) |
                              ((unsigned int)rank << 21);
            sval[loff[lb] + rank] =
                (unsigned long long)pkv[tr] | ((unsigned long long)hi << 32);
        }
        if (lbB[tr] >= 0) {
            int lb = lbB[tr], rank = slB[tr];
            unsigned int hi = qyB[tr] | ((unsigned int)lb << 16) |
                              ((unsigned int)rank << 21);
            sval[loff[lb] + rank] =
                (unsigned long long)pkv[tr] | ((unsigned long long)hi << 32);
        }
    }
    __syncthreads();

    int total = stotal;
    for (int i = tid; i < total; i += 256) {
        unsigned long long v = sval[i];
        unsigned int pk = (unsigned int)v;
        unsigned int hi = (unsigned int)(v >> 32);
        unsigned int qy = hi & 0xffffu;
        int lb   = (hi >> 16) & 31;
        int rank = (hi >> 21) & 1023;
        int gs = gbase[lb] + rank;
        if (gs < CAP) {
            int gbin = (lb >> 4) * (BATCH * BANDS) + b * BANDS + (lb & 15);
            items[(size_t)gbin * CAP + gs] = make_uint2(pk, qy);
        }
    }
}

__device__ __forceinline__ unsigned int pack_w(float w, float tg) {
    unsigned int lo16 = (unsigned int)fmaf(w, 1024.0f, 0.5f);
    unsigned int hi16 = (unsigned int)fmaf(w * tg, 1024.0f, 0.5f);
    return lo16 | (hi16 << 16);
}

// Accumulate one item. Corner adds are packed (w,w*tg) u32 counts; when the
// (left,right) pair is interior and 8B-aligned (even lx), ONE ds_add_u64
// covers both corners. No carry crosses field boundaries (per-pixel 16-bit
// sums stay < 2^16: lambda ~12 adds/pixel, w<=1).
__device__ __forceinline__ void accum_item(unsigned int* __restrict__ s,
                                           unsigned int pk, unsigned int qy) {
    float wx = (float)(pk >> 12) * (1.0f / 2048.0f) - 1.0f;
    float tg = (float)((pk >> 1) & 2047u) * (1.0f / 2047.0f);
    int p = pk & 1u;

    int rowq = qy >> 11;                       // 0..17
    float fy = (float)(qy & 2047u) * (1.0f / 2048.0f);
    int row_top = rowq - 1;                    // -1..16

    float lxf = floorf(wx);
    float fxx = wx - lxf;
    int lx = (int)lxf;

    unsigned int* L = s + p * TILEPIX;

    #pragma unroll
    for (int a = 0; a < 2; ++a) {
        int ry = row_top + a;
        if ((unsigned)ry >= (unsigned)BANDROWS) continue;
        float wrow = a ? fy : (1.0f - fy);
        int rb = ry * WW;
        if (lx >= 0 && lx + 1 < WW) {
            unsigned int pl = pack_w(wrow * (1.0f - fxx), tg);
            unsigned int pr = pack_w(wrow * fxx, tg);
            if ((lx & 1) == 0) {
                unsigned long long v =
                    (unsigned long long)pl | ((unsigned long long)pr << 32);
                atomicAdd((unsigned long long*)(L + rb + lx), v);
            } else {
                atomicAdd(&L[rb + lx], pl);
                atomicAdd(&L[rb + lx + 1], pr);
            }
        } else if (lx == -1) {
            atomicAdd(&L[rb], pack_w(wrow * fxx, tg));
        } else if (lx == WW - 1) {
            atomicAdd(&L[rb + lx], pack_w(wrow * (1.0f - fxx), tg));
        }
    }
}

// Pass 2: one block per bin, 1024 threads, 43 KB LDS (2 blocks/CU).
// uint4 loads (2 items) + software prefetch. Fused ratio^2 loss.
// ONE global atomic per block.
__global__ __launch_bounds__(1024)
void bin_accum(const unsigned int* __restrict__ gcount,
               const uint2* __restrict__ items,
               float* __restrict__ out) {
    __shared__ __align__(8) unsigned int s[2 * TILEPIX];  // [p][pix] packed : 43 KB
    __shared__ float red[16];

    int band = blockIdx.x;
    int tr   = blockIdx.y;
    int b    = blockIdx.z;
    int tid  = threadIdx.x;

    for (int i = tid; i < 2 * TILEPIX; i += 1024) s[i] = 0u;
    __syncthreads();

    int gbin = (tr * BATCH + b) * BANDS + band;
    int cnt = min((int)gcount[gbin], CAP);
    const uint2* bp = items + (size_t)gbin * CAP;
    const uint4* bp4 = (const uint4*)bp;

    int npair = cnt >> 1;
    int n = tid;
    uint4 cur = make_uint4(0u, 0u, 0u, 0u);
    if (n < npair) cur = bp4[n];
    while (n < npair) {
        int nn = n + 1024;
        uint4 nxt = make_uint4(0u, 0u, 0u, 0u);
        if (nn < npair) nxt = bp4[nn];
        accum_item(s, cur.x, cur.y);
        accum_item(s, cur.z, cur.w);
        n = nn;
        cur = nxt;
    }
    if ((cnt & 1) && tid == 0) {
        uint2 u = bp[cnt - 1];
        accum_item(s, u.x, u.y);
    }
    __syncthreads();

    // Fused ratio^2 loss. Counts are (iwe*1024, its*1024); scale cancels.
    float v = 0.0f;
    for (int i = tid; i < 2 * TILEPIX; i += 1024) {
        unsigned int u = s[i];
        float iwe = (float)(u & 0xffffu);
        float its = (float)(u >> 16);
        float r = its / (iwe + 1.024e-6f);
        v += r * r;
    }
    v = wave_reduce_sum(v);
    if ((tid & 63) == 0) red[tid >> 6] = v;
    __syncthreads();
    if (tid < 16) {
        float r = red[tid];
        r += __shfl_down(r, 8, 64);
        r += __shfl_down(r, 4, 64);
        r += __shfl_down(r, 2, 64);
        r += __shfl_down(r, 1, 64);
        if (tid == 0) atomicAdd(out, r);
    }
}

extern "C" void kernel_launch(void* const* d_in, const int* in_sizes, int n_in,
                              void* d_out, int out_size, void* d_ws, size_t ws_size,
                              hipStream_t stream) {
    const float*  flow  = (const float*)d_in[0];
    const float4* ev    = (const float4*)d_in[1];
    float* out = (float*)d_out;

    unsigned int* gcount = (unsigned int*)d_ws;
    uint2* items = (uint2*)((char*)d_ws + 4096);
    float2* flowi = (float2*)((char*)d_ws + 4096 + ITEMS_BYTES);

    hipMemsetAsync(gcount, 0, NBINS * sizeof(unsigned int), stream);
    hipMemsetAsync(d_out, 0, sizeof(float), stream);

    flow_prep<<<512, 256, 0, stream>>>(flow, flowi, out);

    int total_ev = BATCH * NEV;
    bin_events<<<total_ev / 256, 256, 0, stream>>>(flowi, ev, gcount, items);

    dim3 g2(BANDS, 2, BATCH);
    bin_accum<<<g2, 1024, 0, stream>>>(gcount, items, out);
}

// Round 10
// 163.301 us; speedup vs baseline: 2.6649x; 1.0590x over previous
//
#include <hip/hip_runtime.h>

// Problem constants (from reference)
#define HH 256
#define WW 336
#define HWPIX (HH * WW)          // 86016
#define BATCH 8
#define NEV 262144               // 2^18
#define NEV_SHIFT 18
#define FLOW_SCALING 336.0f
#define REG_WEIGHT 0.001f

#define BANDS 16
#define BANDSHIFT 4
#define BANDROWS 16
#define TILEPIX (BANDROWS * WW)    // 5376
#define NBINS (2 * BATCH * BANDS)  // 256 bins: (tr*8+b)*16+band
#define CAP 20480                  // slots/bin; mean ~17.4K, ~+25 sigma headroom

// Workspace layout:
//   [0]        uint   gcount[NBINS]          (1 KB)
//   [4096]     uint2  items[NBINS * CAP]     (40 MB)  (pk, qy16)
//   [after]    float2 flowi[BATCH * HWPIX]   (5.5 MB) interleaved (fx, fy)
// item.x = pk = qx<<12 | qt<<1 | p     (qx = round((wx+1)*2048))
// item.y = qy = round((wy - band*16 + 1) * 2048), band-relative, 16 bits
#define ITEMS_BYTES ((size_t)NBINS * CAP * 8)

__device__ __forceinline__ float wave_reduce_sum(float v) {
    #pragma unroll
    for (int o = 32; o > 0; o >>= 1) v += __shfl_down(v, o, 64);
    return v;
}

__device__ __forceinline__ float charb(float d) { return sqrtf(d * d + 1e-6f); }

// Pre-pass: interleave flow channels (vectorized float4, 4 px/thread) fused
// with the Charbonnier smoothness loss and the gcount zeroing.
__global__ __launch_bounds__(256)
void flow_prep(const float* __restrict__ flow, float2* __restrict__ flowi,
               unsigned int* __restrict__ gcount, float* __restrict__ out) {
    __shared__ float red[4];
    int tid = threadIdx.x;
    if (blockIdx.x == 0) gcount[tid] = 0;   // NBINS == 256

    const int N4 = BATCH * HWPIX / 4;       // 172032 float4 units
    const int H4 = HWPIX / 4;               // 21504
    const int W4 = WW / 4;                  // 84
    float v = 0.0f;
    for (int i = blockIdx.x * 256 + tid; i < N4; i += gridDim.x * 256) {
        int b = i / H4, u = i - b * H4;
        int row = u / W4, c4 = u - row * W4;
        const float4* ch0 = (const float4*)(flow + (size_t)b * 2 * HWPIX);
        const float4* ch1 = ch0 + H4;
        float4 a0 = ch0[u];
        float4 a1 = ch1[u];

        // interleaved store: 4 float2 = 2 float4
        float4* fo = (float4*)(flowi + (size_t)b * HWPIX);
        fo[2 * u]     = make_float4(a0.x, a1.x, a0.y, a1.y);
        fo[2 * u + 1] = make_float4(a0.z, a1.z, a0.w, a1.w);

        if (row < HH - 1) {
            float4 d0 = ch0[u + W4];
            float4 d1 = ch1[u + W4];
            v += charb(a0.x - d0.x) + charb(a0.y - d0.y) +
                 charb(a0.z - d0.z) + charb(a0.w - d0.w) +
                 charb(a1.x - d1.x) + charb(a1.y - d1.y) +
                 charb(a1.z - d1.z) + charb(a1.w - d1.w);
        }
        // horizontal diffs inside the vector
        v += charb(a0.x - a0.y) + charb(a0.y - a0.z) + charb(a0.z - a0.w) +
             charb(a1.x - a1.y) + charb(a1.y - a1.z) + charb(a1.z - a1.w);
        if (c4 < W4 - 1) {
            float r0 = ((const float*)ch0)[4 * u + 4];
            float r1 = ((const float*)ch1)[4 * u + 4];
            v += charb(a0.w - r0) + charb(a1.w - r1);
        }
    }
    v = wave_reduce_sum(v);
    if ((tid & 63) == 0) red[tid >> 6] = v;
    __syncthreads();
    if (tid < 4) {
        float r = red[tid];
        r += __shfl_down(r, 2, 64);
        r += __shfl_down(r, 1, 64);
        if (tid == 0) atomicAdd(out, REG_WEIGHT * r);
    }
}

// Pass 1: warp events, bin by (tr, b, 16-row band); straddling items get one
// copy per band. Staged items carry (qy16 | lb<<16 | rank<<21) so the flush
// recomputes global slots from gbase[lb]+rank. Consecutive staged entries are
// same-bin/consecutive-rank, so pairs merge into one uint4 store when aligned.
#define MAXITEMS 1024
__global__ __launch_bounds__(256)
void bin_events(const float2* __restrict__ flowi,
                const float4* __restrict__ ev,
                unsigned int* __restrict__ gcount,
                uint2* __restrict__ items) {
    __shared__ int lcnt[32];     // local bins: tr*16 + band (b fixed per block)
    __shared__ int loff[32];     // exclusive prefix (LDS staging offset)
    __shared__ int gbase[32];    // global slot base per local bin
    __shared__ int stotal;
    __shared__ __align__(16) unsigned long long sval[MAXITEMS];

    int tid = threadIdx.x;
    if (tid < 32) lcnt[tid] = 0;
    __syncthreads();

    int bn = blockIdx.x * 256 + tid;
    int b = bn >> NEV_SHIFT;     // uniform across block

    float4 e = ev[bn];           // t, y, x, pol(+/-1)
    float t = e.x, y = e.y, x = e.z;
    unsigned int p = (e.w > 0.0f) ? 0u : 1u;   // p=0 <-> pol==+1

    int iy = (int)y, ix = (int)x;   // exact integers in range
    float2 f = flowi[b * HWPIX + iy * WW + ix];
    float fx = f.x, fy = f.y;

    int lbA[2] = {-1, -1}, lbB[2] = {-1, -1};
    int slA[2], slB[2];
    unsigned int qyA[2], qyB[2], pkv[2];

    #pragma unroll
    for (int tr = 0; tr < 2; ++tr) {
        float tref  = tr ? 0.0f : 1.0f;
        float tg    = tr ? (1.0f - t) : t;
        float dtS = (tref - t) * FLOW_SCALING;
        float wy = fmaf(dtS, fy, y);
        float wx = fmaf(dtS, fx, x);
        if (!(wx > -1.0f && wx < (float)WW)) continue;
        if (!(wy > -1.0f && wy < (float)HH)) continue;

        int ty = (int)floorf(wy);
        int band0 = -1, band1 = -1;
        if (ty >= 0 && ty < HH) band0 = ty >> BANDSHIFT;
        int r1 = ty + 1;
        if (r1 >= 0 && r1 < HH) {
            int bb = r1 >> BANDSHIFT;
            if (bb != band0) band1 = bb;
        }

        unsigned int qx = (unsigned int)(fmaf(wx, 2048.0f, 2048.5f));
        unsigned int qt = (unsigned int)(tg * 2047.0f + 0.5f);
        pkv[tr] = (qx << 12) | (qt << 1) | p;

        if (band0 >= 0) {
            float wyrel = wy - (float)(band0 * BANDROWS - 1);   // [1, 17)
            qyA[tr] = (unsigned int)fmaf(wyrel, 2048.0f, 0.5f);
            lbA[tr] = tr * BANDS + band0;
            slA[tr] = atomicAdd(&lcnt[lbA[tr]], 1);
        }
        if (band1 >= 0) {
            float wyrel = wy - (float)(band1 * BANDROWS - 1);   // [0, 1)
            qyB[tr] = (unsigned int)fmaf(wyrel, 2048.0f, 0.5f);
            lbB[tr] = tr * BANDS + band1;
            slB[tr] = atomicAdd(&lcnt[lbB[tr]], 1);
        }
    }
    __syncthreads();

    if (tid < 32) {
        int c = lcnt[tid];
        int xg = c;
        #pragma unroll
        for (int o = 1; o < 32; o <<= 1) {
            int yv = __shfl_up(xg, o, 64);
            if (tid >= o) xg += yv;
        }
        loff[tid] = xg - c;
        if (tid == 31) stotal = xg;
        int gbin = (tid >> 4) * (BATCH * BANDS) + b * BANDS + (tid & 15);
        gbase[tid] = c > 0 ? (int)atomicAdd(&gcount[gbin], (unsigned int)c) : 0;
    }
    __syncthreads();

    #pragma unroll
    for (int tr = 0; tr < 2; ++tr) {
        if (lbA[tr] >= 0) {
            int lb = lbA[tr], rank = slA[tr];
            unsigned int hi = qyA[tr] | ((unsigned int)lb << 16) |
                              ((unsigned int)rank << 21);
            sval[loff[lb] + rank] =
                (unsigned long long)pkv[tr] | ((unsigned long long)hi << 32);
        }
        if (lbB[tr] >= 0) {
            int lb = lbB[tr], rank = slB[tr];
            unsigned int hi = qyB[tr] | ((unsigned int)lb << 16) |
                              ((unsigned int)rank << 21);
            sval[loff[lb] + rank] =
                (unsigned long long)pkv[tr] | ((unsigned long long)hi << 32);
        }
    }
    __syncthreads();

    int total = stotal;
    for (int i = tid * 2; i < total; i += 512) {
        unsigned long long v0 = sval[i];
        unsigned int pk0 = (unsigned int)v0;
        unsigned int h0  = (unsigned int)(v0 >> 32);
        unsigned int qy0 = h0 & 0xffffu;
        int lb0   = (h0 >> 16) & 31;
        int rank0 = (h0 >> 21) & 1023;
        int gs0 = gbase[lb0] + rank0;
        int gbin0 = (lb0 >> 4) * (BATCH * BANDS) + b * BANDS + (lb0 & 15);

        bool has1 = (i + 1) < total;
        if (has1) {
            unsigned long long v1 = sval[i + 1];
            unsigned int pk1 = (unsigned int)v1;
            unsigned int h1  = (unsigned int)(v1 >> 32);
            unsigned int qy1 = h1 & 0xffffu;
            int lb1   = (h1 >> 16) & 31;
            int rank1 = (h1 >> 21) & 1023;
            int gs1 = gbase[lb1] + rank1;
            if (lb1 == lb0 && gs1 == gs0 + 1 && (gs0 & 1) == 0 && gs1 < CAP) {
                *(uint4*)(items + (size_t)gbin0 * CAP + gs0) =
                    make_uint4(pk0, qy0, pk1, qy1);
                continue;
            }
            int gbin1 = (lb1 >> 4) * (BATCH * BANDS) + b * BANDS + (lb1 & 15);
            if (gs1 < CAP) items[(size_t)gbin1 * CAP + gs1] = make_uint2(pk1, qy1);
        }
        if (gs0 < CAP) items[(size_t)gbin0 * CAP + gs0] = make_uint2(pk0, qy0);
    }
}

__device__ __forceinline__ unsigned int pack_w(float w, float tg) {
    unsigned int lo16 = (unsigned int)fmaf(w, 1024.0f, 0.5f);
    unsigned int hi16 = (unsigned int)fmaf(w * tg, 1024.0f, 0.5f);
    return lo16 | (hi16 << 16);
}

// Accumulate one item. Corner adds are packed (w,w*tg) u32 counts; interior
// (left,right) pairs with even lx use ONE ds_add_u64. No carry crosses field
// boundaries (per-pixel 16-bit sums < 2^16: lambda ~12 adds/pixel, w<=1).
__device__ __forceinline__ void accum_item(unsigned int* __restrict__ s,
                                           unsigned int pk, unsigned int qy) {
    float wx = (float)(pk >> 12) * (1.0f / 2048.0f) - 1.0f;
    float tg = (float)((pk >> 1) & 2047u) * (1.0f / 2047.0f);
    int p = pk & 1u;

    int rowq = qy >> 11;                       // 0..17
    float fy = (float)(qy & 2047u) * (1.0f / 2048.0f);
    int row_top = rowq - 1;                    // -1..16

    float lxf = floorf(wx);
    float fxx = wx - lxf;
    int lx = (int)lxf;

    unsigned int* L = s + p * TILEPIX;

    #pragma unroll
    for (int a = 0; a < 2; ++a) {
        int ry = row_top + a;
        if ((unsigned)ry >= (unsigned)BANDROWS) continue;
        float wrow = a ? fy : (1.0f - fy);
        int rb = ry * WW;
        if (lx >= 0 && lx + 1 < WW) {
            unsigned int pl = pack_w(wrow * (1.0f - fxx), tg);
            unsigned int pr = pack_w(wrow * fxx, tg);
            if ((lx & 1) == 0) {
                unsigned long long v =
                    (unsigned long long)pl | ((unsigned long long)pr << 32);
                atomicAdd((unsigned long long*)(L + rb + lx), v);
            } else {
                atomicAdd(&L[rb + lx], pl);
                atomicAdd(&L[rb + lx + 1], pr);
            }
        } else if (lx == -1) {
            atomicAdd(&L[rb], pack_w(wrow * fxx, tg));
        } else if (lx == WW - 1) {
            atomicAdd(&L[rb + lx], pack_w(wrow * (1.0f - fxx), tg));
        }
    }
}

// Pass 2: one block per bin, 1024 threads, 43 KB LDS. 4 items (2 adjacent
// uint4 loads) per iteration. Fused ratio^2 loss; ONE global atomic/block.
__global__ __launch_bounds__(1024)
void bin_accum(const unsigned int* __restrict__ gcount,
               const uint2* __restrict__ items,
               float* __restrict__ out) {
    __shared__ __align__(8) unsigned int s[2 * TILEPIX];  // 43 KB
    __shared__ float red[16];

    int band = blockIdx.x;
    int tr   = blockIdx.y;
    int b    = blockIdx.z;
    int tid  = threadIdx.x;

    for (int i = tid; i < 2 * TILEPIX; i += 1024) s[i] = 0u;
    __syncthreads();

    int gbin = (tr * BATCH + b) * BANDS + band;
    int cnt = min((int)gcount[gbin], CAP);
    const uint2* bp = items + (size_t)gbin * CAP;
    const uint4* bp4 = (const uint4*)bp;

    int nquad = cnt >> 2;
    for (int n = tid; n < nquad; n += 1024) {
        uint4 c0 = bp4[2 * n];
        uint4 c1 = bp4[2 * n + 1];
        accum_item(s, c0.x, c0.y);
        accum_item(s, c0.z, c0.w);
        accum_item(s, c1.x, c1.y);
        accum_item(s, c1.z, c1.w);
    }
    int rem = cnt & 3;
    if (tid < rem) {
        uint2 u = bp[nquad * 4 + tid];
        accum_item(s, u.x, u.y);
    }
    __syncthreads();

    // Fused ratio^2 loss. Counts are (iwe*1024, its*1024); scale cancels.
    float v = 0.0f;
    for (int i = tid; i < 2 * TILEPIX; i += 1024) {
        unsigned int u = s[i];
        float iwe = (float)(u & 0xffffu);
        float its = (float)(u >> 16);
        float r = its / (iwe + 1.024e-6f);
        v += r * r;
    }
    v = wave_reduce_sum(v);
    if ((tid & 63) == 0) red[tid >> 6] = v;
    __syncthreads();
    if (tid < 16) {
        float r = red[tid];
        r += __shfl_down(r, 8, 64);
        r += __shfl_down(r, 4, 64);
        r += __shfl_down(r, 2, 64);
        r += __shfl_down(r, 1, 64);
        if (tid == 0) atomicAdd(out, r);
    }
}

extern "C" void kernel_launch(void* const* d_in, const int* in_sizes, int n_in,
                              void* d_out, int out_size, void* d_ws, size_t ws_size,
                              hipStream_t stream) {
    const float*  flow  = (const float*)d_in[0];
    const float4* ev    = (const float4*)d_in[1];
    float* out = (float*)d_out;

    unsigned int* gcount = (unsigned int*)d_ws;
    uint2* items = (uint2*)((char*)d_ws + 4096);
    float2* flowi = (float2*)((char*)d_ws + 4096 + ITEMS_BYTES);

    hipMemsetAsync(d_out, 0, sizeof(float), stream);

    flow_prep<<<512, 256, 0, stream>>>(flow, flowi, gcount, out);

    int total_ev = BATCH * NEV;
    bin_events<<<total_ev / 256, 256, 0, stream>>>(flowi, ev, gcount, items);

    dim3 g2(BANDS, 2, BATCH);
    bin_accum<<<g2, 1024, 0, stream>>>(gcount, items, out);
}